// Round 1
// baseline (4923.979 us; speedup 1.0000x reference)
//
#include <hip/hip_runtime.h>
#include <cstdint>
#include <cstddef>

#define NB 128
#define NC 16
#define NT 2048
#define NH 256
#define NG 1024
#define NO 10

typedef _Float16 f16;
typedef _Float16 h2 __attribute__((ext_vector_type(2)));
typedef _Float16 h8 __attribute__((ext_vector_type(8)));

static __device__ __forceinline__ float fdot2(h2 a, h2 b, float c) {
#if __has_builtin(__builtin_amdgcn_fdot2)
  return __builtin_amdgcn_fdot2(a, b, c, false);
#else
  return c + (float)a[0] * (float)b[0] + (float)a[1] * (float)b[1];
#endif
}

static __device__ __forceinline__ float sigm(float x) {
  return __builtin_amdgcn_rcpf(1.f + __expf(-x));
}
static __device__ __forceinline__ float tanh_(float x) {
  // tanh(x) = 1 - 2/(exp(2x)+1); saturates correctly for |x| large (exp->inf/0)
  return 1.f - 2.f * __builtin_amdgcn_rcpf(1.f + __expf(2.f * x));
}

// Repack w_hh (1024x256 fp32, row-major) into k-major f16:
//   wp[((k>>3)*1024 + row)*8 + (k&7)] = (f16) w_hh[row*256 + k]
// so that for a fixed 8-wide k-chunk, lane j reading row j is a coalesced
// 16 B/lane load (both for the one-time register fill and the LDS fill).
__global__ void prepack_whh(const float* __restrict__ whh, f16* __restrict__ wp) {
  int row = blockIdx.x;   // 0..1023
  int k   = threadIdx.x;  // 0..255
  float v = whh[row * NH + k];
  wp[((size_t)(k >> 3) * NG + (size_t)row) * 8 + (k & 7)] = (f16)v;
}

// One workgroup per batch. Thread j owns hidden unit j: gate rows
// i=j, f=256+j, g=512+j, o=768+j. i,f,g rows live in VGPRs (384 regs of
// packed f16 pairs); o row lives in LDS (128 KB). h is double-buffered f16
// in LDS (broadcast reads). Cell state c stays in an fp32 register.
__global__ __launch_bounds__(256, 1)
void lstm_main(const float* __restrict__ x,
               const float* __restrict__ w_ih,
               const float* __restrict__ b_ih,
               const float* __restrict__ b_hh,
               const float* __restrict__ w_out,
               const float* __restrict__ b_out,
               const f16* __restrict__ wp,
               float* __restrict__ out) {
  const int j = threadIdx.x;  // 0..255
  const int b = blockIdx.x;   // 0..127

  __shared__ __align__(16) f16 olds[32][NH][8];  // 128 KB: o-gate rows, k-major chunks
  __shared__ __align__(16) f16 hbuf[2][NH];      // 1 KB: h double buffer (f16)
  __shared__ __align__(16) f16 xs[64][NC];       // 2 KB: staged x chunk (f16)
  __shared__ __align__(16) float hT[NH];
  __shared__ float lg[NO];

  // ---------------- one-time loads ----------------
  h2 wi_[128], wf_[128], wg_[128];  // i,f,g rows, 128 packed pairs each
  h2 wih[4][8];                     // w_ih rows (16 ch = 8 pairs) x 4 gates
  const h8* wp8 = (const h8*)wp;
#pragma unroll
  for (int q = 0; q < 32; ++q) {
    h8 vi = wp8[(size_t)q * NG + j];
    h8 vf = wp8[(size_t)q * NG + 256 + j];
    h8 vg = wp8[(size_t)q * NG + 512 + j];
    h8 vo = wp8[(size_t)q * NG + 768 + j];
#pragma unroll
    for (int u = 0; u < 4; ++u) {
      h2 ti = {vi[2 * u], vi[2 * u + 1]}; wi_[4 * q + u] = ti;
      h2 tf = {vf[2 * u], vf[2 * u + 1]}; wf_[4 * q + u] = tf;
      h2 tg = {vg[2 * u], vg[2 * u + 1]}; wg_[4 * q + u] = tg;
    }
    *(h8*)&olds[q][j][0] = vo;  // private: only thread j ever reads olds[*][j]
  }
#pragma unroll
  for (int g4 = 0; g4 < 4; ++g4) {
    int row = j + 256 * g4;
#pragma unroll
    for (int u = 0; u < 8; ++u) {
      h2 t2 = {(f16)w_ih[row * NC + 2 * u], (f16)w_ih[row * NC + 2 * u + 1]};
      wih[g4][u] = t2;
    }
  }
  float bi_ = b_ih[j] + b_hh[j];
  float bf_ = b_ih[256 + j] + b_hh[256 + j];
  float bg_ = b_ih[512 + j] + b_hh[512 + j];
  float bo_ = b_ih[768 + j] + b_hh[768 + j];

  // init h = 0, stage x chunk 0
  if (j < 128) {
    h2 z = {(f16)0.f, (f16)0.f};
    ((h2*)&hbuf[0][0])[j] = z;
  }
#pragma unroll
  for (int r = 0; r < 4; ++r) {
    int e = j + 256 * r;  // 0..1023 over (c, tt)
    int cc = e >> 6, tt = e & 63;
    xs[tt][cc] = (f16)x[(size_t)(b * NC + cc) * NT + tt];
  }
  __syncthreads();

  // ---------------- recurrence ----------------
  float c_ = 0.f, h_last = 0.f;
  const h8* obase = (const h8*)&olds[0][j][0];  // stride NH h8 per k-chunk

#pragma unroll 1
  for (int s = 0; s < NT; ++s) {
    const int p = s & 1;
    // anti-LICM: make the o-row address opaquely loop-variant so the 32
    // ds_read_b128 of the (constant) o weights can't be hoisted into regs.
    int zero = 0;
    asm volatile("" : "+s"(zero));
    const h8* ob = obase + zero;
    const h8* hsrc = (const h8*)&hbuf[p][0];

    float ai = bi_, af = bf_, ag = bg_, ao = bo_;

    // x projection: 16 channels = 8 f16 pairs
    {
      const h8* xr = (const h8*)&xs[s & 63][0];
      h8 x0 = xr[0], x1 = xr[1];
#pragma unroll
      for (int u = 0; u < 4; ++u) {
        h2 xp0 = {x0[2 * u], x0[2 * u + 1]};
        ai = fdot2(xp0, wih[0][u], ai);
        af = fdot2(xp0, wih[1][u], af);
        ag = fdot2(xp0, wih[2][u], ag);
        ao = fdot2(xp0, wih[3][u], ao);
        h2 xp1 = {x1[2 * u], x1[2 * u + 1]};
        ai = fdot2(xp1, wih[0][u + 4], ai);
        af = fdot2(xp1, wih[1][u + 4], af);
        ag = fdot2(xp1, wih[2][u + 4], ag);
        ao = fdot2(xp1, wih[3][u + 4], ao);
      }
    }

    // recurrent dots: h (broadcast from LDS) against i,f,g (regs) + o (LDS)
#pragma unroll
    for (int q = 0; q < 32; ++q) {
      h8 hv = hsrc[q];                 // same addr across lanes: broadcast
      h8 ov = ob[(size_t)q * NH];      // per-thread private row
#pragma unroll
      for (int u = 0; u < 4; ++u) {
        h2 hp = {hv[2 * u], hv[2 * u + 1]};
        h2 op = {ov[2 * u], ov[2 * u + 1]};
        ai = fdot2(hp, wi_[4 * q + u], ai);
        af = fdot2(hp, wf_[4 * q + u], af);
        ag = fdot2(hp, wg_[4 * q + u], ag);
        ao = fdot2(hp, op, ao);
      }
    }

    float ig = sigm(ai);
    float fg = sigm(af);
    float gv = tanh_(ag);
    float og = sigm(ao);
    c_ = fg * c_ + ig * gv;
    float hh = og * tanh_(c_);
    hbuf[1 - p][j] = (f16)hh;
    h_last = hh;

    // restage x every 64 steps (extra barrier protects WAR on xs)
    if ((s & 63) == 63 && s != NT - 1) {
      __syncthreads();
      int t0 = s + 1;
#pragma unroll
      for (int r = 0; r < 4; ++r) {
        int e = j + 256 * r;
        int cc = e >> 6, tt = e & 63;
        xs[tt][cc] = (f16)x[(size_t)(b * NC + cc) * NT + t0 + tt];
      }
    }
    __syncthreads();
  }

  // ---------------- head: logits + log_softmax ----------------
  hT[j] = h_last;
  __syncthreads();
  if (j < NO) {
    float acc = b_out[j];
    for (int k = 0; k < NH; ++k) acc += hT[k] * w_out[j * NH + k];
    lg[j] = acc;
  }
  __syncthreads();
  if (j == 0) {
    float m = lg[0];
    for (int o = 1; o < NO; ++o) m = fmaxf(m, lg[o]);
    float ssum = 0.f;
    for (int o = 0; o < NO; ++o) ssum += __expf(lg[o] - m);
    float lse = m + __logf(ssum);
    for (int o = 0; o < NO; ++o) out[b * NO + o] = lg[o] - lse;
  }
}

extern "C" void kernel_launch(void* const* d_in, const int* in_sizes, int n_in,
                              void* d_out, int out_size, void* d_ws, size_t ws_size,
                              hipStream_t stream) {
  const float* x    = (const float*)d_in[0];
  const float* wih  = (const float*)d_in[1];
  const float* whh  = (const float*)d_in[2];
  const float* bih  = (const float*)d_in[3];
  const float* bhh  = (const float*)d_in[4];
  const float* wout = (const float*)d_in[5];
  const float* bout = (const float*)d_in[6];
  float* out = (float*)d_out;
  f16* wp = (f16*)d_ws;  // 512 KB f16 repack of w_hh

  hipLaunchKernelGGL(prepack_whh, dim3(NG), dim3(NH), 0, stream, whh, wp);
  hipLaunchKernelGGL(lstm_main, dim3(NB), dim3(256), 0, stream,
                     x, wih, bih, bhh, wout, bout, wp, out);
}

// Round 2
// 3015.676 us; speedup vs baseline: 1.6328x; 1.6328x over previous
//
#include <hip/hip_runtime.h>
#include <cstdint>
#include <cstddef>

#define NB 128
#define NC 16
#define NT 2048
#define NH 256
#define NG 1024
#define NO 10

typedef _Float16 f16;
typedef _Float16 h2 __attribute__((ext_vector_type(2)));
typedef _Float16 h8 __attribute__((ext_vector_type(8)));

static __device__ __forceinline__ float fdot2(h2 a, h2 b, float c) {
#if __has_builtin(__builtin_amdgcn_fdot2)
  return __builtin_amdgcn_fdot2(a, b, c, false);
#else
  return c + (float)a[0] * (float)b[0] + (float)a[1] * (float)b[1];
#endif
}

static __device__ __forceinline__ float sigm(float x) {
  return __builtin_amdgcn_rcpf(1.f + __expf(-x));
}
static __device__ __forceinline__ float tanh_(float x) {
  return 1.f - 2.f * __builtin_amdgcn_rcpf(1.f + __expf(2.f * x));
}

// Repack w_hh (1024x256 fp32, row-major) into k-chunk-major f16:
//   wp[((k>>3)*1024 + row)*8 + (k&7)] = (f16) w_hh[row*256 + k]
__global__ void prepack_whh(const float* __restrict__ whh, f16* __restrict__ wp) {
  int row = blockIdx.x;   // 0..1023
  int k   = threadIdx.x;  // 0..255
  float v = whh[row * NH + k];
  wp[((size_t)(k >> 3) * NG + (size_t)row) * 8 + (k & 7)] = (f16)v;
}

// One workgroup per batch, 512 threads (8 waves -> 2 waves/SIMD).
// Thread t = 2*u + half owns hidden unit u and k-half `half` (k in
// [128*half, 128*half+128)). i,f,g half-rows in VGPRs (192 h2 regs);
// o half-rows stream from LDS (128 KB); h double-buffered f16 in LDS.
// Pair-reduce partial gate sums with shfl_xor(1); both lanes keep an
// identical copy of the cell state (commutative add => bit-identical).
__global__ __launch_bounds__(512, 2)
void lstm_main(const float* __restrict__ x,
               const float* __restrict__ w_ih,
               const float* __restrict__ b_ih,
               const float* __restrict__ b_hh,
               const float* __restrict__ w_out,
               const float* __restrict__ b_out,
               const f16* __restrict__ wp,
               float* __restrict__ out) {
  const int t = threadIdx.x;   // 0..511
  const int u = t >> 1;        // hidden unit 0..255
  const int half = t & 1;      // k-half
  const int b = blockIdx.x;

  __shared__ __align__(16) f16 olds[32][NH][8];  // 128 KB: o rows, [kchunk][unit][8]
  __shared__ __align__(16) f16 hbuf[2][NH];      // 1 KB
  __shared__ __align__(16) f16 xs[64][NC];       // 2 KB
  __shared__ float hT[NH];
  __shared__ float lg[NO];

  // ---------------- one-time loads ----------------
  h2 wi_[64], wf_[64], wg_[64];  // i,f,g half-rows (64 packed pairs each)
  h2 wih[4][4];                  // w_ih half-rows (8 ch = 4 pairs) x 4 gates
  const h8* wp8 = (const h8*)wp;
  const int q0 = half * 16;      // this thread's k-chunk range
#pragma unroll
  for (int q = 0; q < 16; ++q) {
    h8 vi = wp8[(size_t)(q0 + q) * NG + u];
    h8 vf = wp8[(size_t)(q0 + q) * NG + 256 + u];
    h8 vg = wp8[(size_t)(q0 + q) * NG + 512 + u];
    h8 vo = wp8[(size_t)(q0 + q) * NG + 768 + u];
#pragma unroll
    for (int uu = 0; uu < 4; ++uu) {
      h2 ti = {vi[2 * uu], vi[2 * uu + 1]}; wi_[4 * q + uu] = ti;
      h2 tf = {vf[2 * uu], vf[2 * uu + 1]}; wf_[4 * q + uu] = tf;
      h2 tg = {vg[2 * uu], vg[2 * uu + 1]}; wg_[4 * q + uu] = tg;
    }
    *(h8*)&olds[q0 + q][u][0] = vo;  // read back only by this thread
  }
#pragma unroll
  for (int g4 = 0; g4 < 4; ++g4) {
    int row = u + 256 * g4;
#pragma unroll
    for (int uu = 0; uu < 4; ++uu) {
      h2 t2 = {(f16)w_ih[row * NC + half * 8 + 2 * uu],
               (f16)w_ih[row * NC + half * 8 + 2 * uu + 1]};
      wih[g4][uu] = t2;
    }
  }
  // biases only in half 0 (added exactly once per gate sum)
  float bi_ = half ? 0.f : b_ih[u] + b_hh[u];
  float bf_ = half ? 0.f : b_ih[256 + u] + b_hh[256 + u];
  float bg_ = half ? 0.f : b_ih[512 + u] + b_hh[512 + u];
  float bo_ = half ? 0.f : b_ih[768 + u] + b_hh[768 + u];

  // init h = 0, stage x chunk 0
  if (t < 128) {
    h2 z = {(f16)0.f, (f16)0.f};
    ((h2*)&hbuf[0][0])[t] = z;
  }
#pragma unroll
  for (int r = 0; r < 2; ++r) {
    int e = t + 512 * r;  // 0..1023 over (c, tt)
    int cc = e >> 6, tt = e & 63;
    xs[tt][cc] = (f16)x[(size_t)(b * NC + cc) * NT + tt];
  }
  __syncthreads();

  // ---------------- recurrence ----------------
  float c_ = 0.f, h_last = 0.f;
  const h8* obase = (const h8*)&olds[q0][u][0];  // chunk stride = NH h8

#pragma unroll 1
  for (int s = 0; s < NT; ++s) {
    const int p = s & 1;
    // anti-LICM: opaque zero so the (constant) o-weight LDS reads can't be
    // hoisted out of the loop into 256 registers.
    int zero = 0;
    asm volatile("" : "+s"(zero));
    const h8* ob = obase + zero;
    const h8* hsrc = (const h8*)&hbuf[p][half * 128];

    float ai = bi_, af = bf_, ag = bg_, ao = bo_;

    // x projection: this half's 8 channels = 4 f16 pairs
    {
      h8 xv = *(const h8*)&xs[s & 63][half * 8];
#pragma unroll
      for (int uu = 0; uu < 4; ++uu) {
        h2 xp = {xv[2 * uu], xv[2 * uu + 1]};
        ai = fdot2(xp, wih[0][uu], ai);
        af = fdot2(xp, wih[1][uu], af);
        ag = fdot2(xp, wih[2][uu], ag);
        ao = fdot2(xp, wih[3][uu], ao);
      }
    }

    // recurrent dots over this thread's 128-wide k-half
#pragma unroll
    for (int q = 0; q < 16; ++q) {
      h8 hv = hsrc[q];                 // 2 distinct addrs/wave (broadcast)
      h8 ov = ob[(size_t)q * NH];      // private 16B chunk per lane
#pragma unroll
      for (int uu = 0; uu < 4; ++uu) {
        h2 hp = {hv[2 * uu], hv[2 * uu + 1]};
        h2 op = {ov[2 * uu], ov[2 * uu + 1]};
        ai = fdot2(hp, wi_[4 * q + uu], ai);
        af = fdot2(hp, wf_[4 * q + uu], af);
        ag = fdot2(hp, wg_[4 * q + uu], ag);
        ao = fdot2(hp, op, ao);
      }
    }

    // pair reduction across the two k-halves (lanes 2u, 2u+1)
    ai += __shfl_xor(ai, 1, 64);
    af += __shfl_xor(af, 1, 64);
    ag += __shfl_xor(ag, 1, 64);
    ao += __shfl_xor(ao, 1, 64);

    float ig = sigm(ai);
    float fg = sigm(af);
    float gv = tanh_(ag);
    float og = sigm(ao);
    c_ = fg * c_ + ig * gv;
    float hh = og * tanh_(c_);
    if (!half) hbuf[1 - p][u] = (f16)hh;
    h_last = hh;

    // restage x every 64 steps (extra barrier protects WAR on xs)
    if ((s & 63) == 63 && s != NT - 1) {
      __syncthreads();
      int t0v = s + 1;
#pragma unroll
      for (int r = 0; r < 2; ++r) {
        int e = t + 512 * r;
        int cc = e >> 6, tt = e & 63;
        xs[tt][cc] = (f16)x[(size_t)(b * NC + cc) * NT + t0v + tt];
      }
    }
    __syncthreads();
  }

  // ---------------- head: logits + log_softmax ----------------
  if (!half) hT[u] = h_last;
  __syncthreads();
  if (t < NO) {
    float acc = b_out[t];
    for (int k = 0; k < NH; ++k) acc += hT[k] * w_out[t * NH + k];
    lg[t] = acc;
  }
  __syncthreads();
  if (t == 0) {
    float m = lg[0];
    for (int o = 1; o < NO; ++o) m = fmaxf(m, lg[o]);
    float ssum = 0.f;
    for (int o = 0; o < NO; ++o) ssum += __expf(lg[o] - m);
    float lse = m + __logf(ssum);
    for (int o = 0; o < NO; ++o) out[b * NO + o] = lg[o] - lse;
  }
}

extern "C" void kernel_launch(void* const* d_in, const int* in_sizes, int n_in,
                              void* d_out, int out_size, void* d_ws, size_t ws_size,
                              hipStream_t stream) {
  const float* x    = (const float*)d_in[0];
  const float* wih  = (const float*)d_in[1];
  const float* whh  = (const float*)d_in[2];
  const float* bih  = (const float*)d_in[3];
  const float* bhh  = (const float*)d_in[4];
  const float* wout = (const float*)d_in[5];
  const float* bout = (const float*)d_in[6];
  float* out = (float*)d_out;
  f16* wp = (f16*)d_ws;  // 512 KB f16 repack of w_hh

  hipLaunchKernelGGL(prepack_whh, dim3(NG), dim3(NH), 0, stream, whh, wp);
  hipLaunchKernelGGL(lstm_main, dim3(NB), dim3(512), 0, stream,
                     x, wih, bih, bhh, wout, bout, wp, out);
}

// Round 3
// 2974.052 us; speedup vs baseline: 1.6556x; 1.0140x over previous
//
#include <hip/hip_runtime.h>
#include <cstdint>
#include <cstddef>

#define NB 128
#define NC 16
#define NT 2048
#define NH 256
#define NG 1024
#define NO 10

typedef _Float16 f16;
typedef _Float16 h2 __attribute__((ext_vector_type(2)));
typedef _Float16 h8 __attribute__((ext_vector_type(8)));

static __device__ __forceinline__ float fdot2(h2 a, h2 b, float c) {
#if __has_builtin(__builtin_amdgcn_fdot2)
  return __builtin_amdgcn_fdot2(a, b, c, false);
#else
  return c + (float)a[0] * (float)b[0] + (float)a[1] * (float)b[1];
#endif
}

// Swap values between adjacent lanes (2u <-> 2u+1) on the VALU via DPP
// quad_perm [1,0,3,2] — avoids the DS-pipe ds_swizzle that __shfl_xor emits.
static __device__ __forceinline__ float pairswap(float v) {
#if __has_builtin(__builtin_amdgcn_update_dpp)
  int r = __builtin_amdgcn_update_dpp(0, __builtin_bit_cast(int, v),
                                      0xB1, 0xF, 0xF, true);
  return __builtin_bit_cast(float, r);
#else
  return __shfl_xor(v, 1, 64);
#endif
}

static __device__ __forceinline__ float sigm(float x) {
  return __builtin_amdgcn_rcpf(1.f + __expf(-x));
}
static __device__ __forceinline__ float tanh_(float x) {
  return 1.f - 2.f * __builtin_amdgcn_rcpf(1.f + __expf(2.f * x));
}

// Repack w_hh (1024x256 fp32, row-major) into k-chunk-major f16:
//   wp[((k>>3)*1024 + row)*8 + (k&7)] = (f16) w_hh[row*256 + k]
__global__ void prepack_whh(const float* __restrict__ whh, f16* __restrict__ wp) {
  int row = blockIdx.x;   // 0..1023
  int k   = threadIdx.x;  // 0..255
  float v = whh[row * NH + k];
  wp[((size_t)(k >> 3) * NG + (size_t)row) * 8 + (k & 7)] = (f16)v;
}

// One workgroup per batch, 512 threads (8 waves -> 2 waves/SIMD).
// Thread t = 2*u + half owns hidden unit u and k-half `half`.
// i,f,g half-rows in VGPRs (192 h2 regs); o half-rows stream from LDS,
// stored thread-major so each wave's ds_read_b128 is lane-contiguous
// (conflict-free); h double-buffered f16 in LDS (2-addr broadcast reads).
// Pair-reduce partial gate sums with a DPP lane swap (VALU, not DS).
__global__ __launch_bounds__(512, 2)
void lstm_main(const float* __restrict__ x,
               const float* __restrict__ w_ih,
               const float* __restrict__ b_ih,
               const float* __restrict__ b_hh,
               const float* __restrict__ w_out,
               const float* __restrict__ b_out,
               const f16* __restrict__ wp,
               float* __restrict__ out) {
  const int t = threadIdx.x;   // 0..511
  const int u = t >> 1;        // hidden unit 0..255
  const int half = t & 1;      // k-half
  const int b = blockIdx.x;

  __shared__ __align__(16) f16 olds2[16][512][8];  // 128 KB, [kchunk][thread][8]
  __shared__ __align__(16) f16 hbuf[2][NH];        // 1 KB
  __shared__ __align__(16) f16 xs[64][NC];         // 2 KB
  __shared__ float hT[NH];
  __shared__ float lg[NO];

  // ---------------- one-time loads ----------------
  h2 wi_[64], wf_[64], wg_[64];  // i,f,g half-rows (64 packed pairs each)
  h2 wih[4][4];                  // w_ih half-rows (8 ch = 4 pairs) x 4 gates
  const h8* wp8 = (const h8*)wp;
  const int q0 = half * 16;      // this thread's k-chunk range
#pragma unroll
  for (int q = 0; q < 16; ++q) {
    h8 vi = wp8[(size_t)(q0 + q) * NG + u];
    h8 vf = wp8[(size_t)(q0 + q) * NG + 256 + u];
    h8 vg = wp8[(size_t)(q0 + q) * NG + 512 + u];
    h8 vo = wp8[(size_t)(q0 + q) * NG + 768 + u];
#pragma unroll
    for (int uu = 0; uu < 4; ++uu) {
      h2 ti = {vi[2 * uu], vi[2 * uu + 1]}; wi_[4 * q + uu] = ti;
      h2 tf = {vf[2 * uu], vf[2 * uu + 1]}; wf_[4 * q + uu] = tf;
      h2 tg = {vg[2 * uu], vg[2 * uu + 1]}; wg_[4 * q + uu] = tg;
    }
    *(h8*)&olds2[q][t][0] = vo;  // read back only by this thread
  }
#pragma unroll
  for (int g4 = 0; g4 < 4; ++g4) {
    int row = u + 256 * g4;
#pragma unroll
    for (int uu = 0; uu < 4; ++uu) {
      h2 t2 = {(f16)w_ih[row * NC + half * 8 + 2 * uu],
               (f16)w_ih[row * NC + half * 8 + 2 * uu + 1]};
      wih[g4][uu] = t2;
    }
  }
  // biases only in half 0 (added exactly once per gate sum)
  float bi_ = half ? 0.f : b_ih[u] + b_hh[u];
  float bf_ = half ? 0.f : b_ih[256 + u] + b_hh[256 + u];
  float bg_ = half ? 0.f : b_ih[512 + u] + b_hh[512 + u];
  float bo_ = half ? 0.f : b_ih[768 + u] + b_hh[768 + u];

  // init h = 0, stage x chunk 0
  if (t < 128) {
    h2 z = {(f16)0.f, (f16)0.f};
    ((h2*)&hbuf[0][0])[t] = z;
  }
#pragma unroll
  for (int r = 0; r < 2; ++r) {
    int e = t + 512 * r;  // 0..1023 over (c, tt)
    int cc = e >> 6, tt = e & 63;
    xs[tt][cc] = (f16)x[(size_t)(b * NC + cc) * NT + tt];
  }
  __syncthreads();

  // ---------------- recurrence ----------------
  float c_ = 0.f, h_last = 0.f;
  const h8* obase = (const h8*)&olds2[0][t][0];  // chunk stride = 512 h8

#pragma unroll 1
  for (int s = 0; s < NT; ++s) {
    const int p = s & 1;
    // anti-LICM: opaque zero so the (constant) o-weight LDS reads can't be
    // hoisted out of the loop into registers.
    int zero = 0;
    asm volatile("" : "+s"(zero));
    const h8* ob = obase + zero;
    const h8* hsrc = (const h8*)&hbuf[p][half * 128];

    float ai = bi_, af = bf_, ag = bg_, ao = bo_;

    // x projection: this half's 8 channels = 4 f16 pairs
    {
      h8 xv = *(const h8*)&xs[s & 63][half * 8];
#pragma unroll
      for (int uu = 0; uu < 4; ++uu) {
        h2 xp = {xv[2 * uu], xv[2 * uu + 1]};
        ai = fdot2(xp, wih[0][uu], ai);
        af = fdot2(xp, wih[1][uu], af);
        ag = fdot2(xp, wih[2][uu], ag);
        ao = fdot2(xp, wih[3][uu], ao);
      }
    }

    // recurrent dots over this thread's 128-wide k-half
#pragma unroll
    for (int q = 0; q < 16; ++q) {
      h8 hv = hsrc[q];                 // 2 distinct addrs/wave (broadcast)
      h8 ov = ob[(size_t)q * 512];     // lane-contiguous: conflict-free
#pragma unroll
      for (int uu = 0; uu < 4; ++uu) {
        h2 hp = {hv[2 * uu], hv[2 * uu + 1]};
        h2 op = {ov[2 * uu], ov[2 * uu + 1]};
        ai = fdot2(hp, wi_[4 * q + uu], ai);
        af = fdot2(hp, wf_[4 * q + uu], af);
        ag = fdot2(hp, wg_[4 * q + uu], ag);
        ao = fdot2(hp, op, ao);
      }
    }

    // pair reduction across the two k-halves (lanes 2u, 2u+1) via DPP
    ai += pairswap(ai);
    af += pairswap(af);
    ag += pairswap(ag);
    ao += pairswap(ao);

    float ig = sigm(ai);
    float fg = sigm(af);
    float gv = tanh_(ag);
    float og = sigm(ao);
    c_ = fg * c_ + ig * gv;
    float hh = og * tanh_(c_);
    if (!half) hbuf[1 - p][u] = (f16)hh;
    h_last = hh;

    // restage x every 64 steps (extra barrier protects WAR on xs)
    if ((s & 63) == 63 && s != NT - 1) {
      __syncthreads();
      int t0v = s + 1;
#pragma unroll
      for (int r = 0; r < 2; ++r) {
        int e = t + 512 * r;
        int cc = e >> 6, tt = e & 63;
        xs[tt][cc] = (f16)x[(size_t)(b * NC + cc) * NT + t0v + tt];
      }
    }
    __syncthreads();
  }

  // ---------------- head: logits + log_softmax ----------------
  if (!half) hT[u] = h_last;
  __syncthreads();
  if (t < NO) {
    float acc = b_out[t];
    for (int k = 0; k < NH; ++k) acc += hT[k] * w_out[t * NH + k];
    lg[t] = acc;
  }
  __syncthreads();
  if (t == 0) {
    float m = lg[0];
    for (int o = 1; o < NO; ++o) m = fmaxf(m, lg[o]);
    float ssum = 0.f;
    for (int o = 0; o < NO; ++o) ssum += __expf(lg[o] - m);
    float lse = m + __logf(ssum);
    for (int o = 0; o < NO; ++o) out[b * NO + o] = lg[o] - lse;
  }
}

extern "C" void kernel_launch(void* const* d_in, const int* in_sizes, int n_in,
                              void* d_out, int out_size, void* d_ws, size_t ws_size,
                              hipStream_t stream) {
  const float* x    = (const float*)d_in[0];
  const float* wih  = (const float*)d_in[1];
  const float* whh  = (const float*)d_in[2];
  const float* bih  = (const float*)d_in[3];
  const float* bhh  = (const float*)d_in[4];
  const float* wout = (const float*)d_in[5];
  const float* bout = (const float*)d_in[6];
  float* out = (float*)d_out;
  f16* wp = (f16*)d_ws;  // 512 KB f16 repack of w_hh

  hipLaunchKernelGGL(prepack_whh, dim3(NG), dim3(NH), 0, stream, whh, wp);
  hipLaunchKernelGGL(lstm_main, dim3(NB), dim3(512), 0, stream,
                     x, wih, bih, bhh, wout, bout, wp, out);
}